// Round 11
// baseline (41.428 us; speedup 1.0000x reference)
//
#include <hip/hip_runtime.h>
#include <hip/hip_bf16.h>
#include <math.h>

// Gaussian upsampling, round 11: single-barrier pipeline, B-in-registers.
//   K0 transpose_enc_bf16 : enc -> pre-permuted encT (validated R10)
//   K1 gauss_fused2       : grid 512, 512 thr (8 waves). Block = (b, dh, 256 rows
//                           = 4 tiles of 64). B-frags (16 x bf16x8) in VGPRs,
//                           loaded once from global. Per tile, ONE raw s_barrier:
//       phase(t): winv(t) | epilogue(t-1) direct stores | kloop(t) A[t&1]+Breg
//                 | exp(t+1)->A[t^1] (b128 writes)  -> lgkmcnt(0); s_barrier
//   (no vmcnt drain at barriers: stores are write-once, never read back)

typedef short  bf16x8 __attribute__((ext_vector_type(8)));
typedef float  f32x4  __attribute__((ext_vector_type(4)));
typedef int    i32x4  __attribute__((ext_vector_type(4)));
typedef unsigned short u16x8 __attribute__((ext_vector_type(8)));

#define S_FIX 256
#define D_FIX 256
#define BM    64      // t-rows per tile
#define NTILE 4       // tiles per block (256 rows)

static __device__ __forceinline__ unsigned short f2bf(float f) {
    union { float f; unsigned u; } v; v.f = f;
    unsigned r = v.u + 0x7FFFu + ((v.u >> 16) & 1u);   // RNE
    return (unsigned short)(r >> 16);
}

static __device__ __forceinline__ unsigned pack_bf2(float lo, float hi) {
    float2 v; v.x = lo; v.y = hi;
    union { __hip_bfloat162 h; unsigned u; } c;
    c.h = __float22bfloat162_rn(v);
    return c.u;   // low16 = bf16(lo), high16 = bf16(hi)
}

// ---------------- K0: enc -> encT (pre-permuted; validated R10) ----------------
__global__ __launch_bounds__(256) void transpose_enc_bf16(
    const float* __restrict__ enc, unsigned short* __restrict__ encT)
{
    const int g  = blockIdx.x * 256 + threadIdx.x;
    const int d  = g & 255;
    const int sc = (g >> 8) & 31;     // 8-s chunk
    const int b  = g >> 13;
    const int s0 = sc * 8;
    const float* p = enc + ((size_t)b << 16) + (size_t)s0 * D_FIX + d;
    u16x8 v;
    #pragma unroll
    for (int j = 0; j < 8; ++j) v[j] = f2bf(p[(size_t)j * D_FIX]);
    const int dh = d >> 7, dl = d & 127;
    const size_t off = ((size_t)b << 17) + ((size_t)dh << 16)
                     + (size_t)dl * 512 + (unsigned)((16 * sc) ^ ((dl & 15) << 4));
    *(u16x8*)((char*)encT + off) = v;
}

// ---------------- K1: pipelined fused main ----------------
__global__ __launch_bounds__(512) void gauss_fused2(
    const float* __restrict__ dur,            // (B,S)
    const float* __restrict__ rng,            // (B,S,1)
    const unsigned short* __restrict__ encT,  // permuted (B,2,128,256)
    float* __restrict__ out,                  // (B,T,D)
    int T)
{
    __shared__ __align__(16) short s_A[2][BM * S_FIX];   // 2 x 32 KB
    __shared__ float s_c[S_FIX];
    __shared__ float s_nir[S_FIX];
    __shared__ float s_part[2][8][BM];
    __shared__ float s_winv[2][BM];

    const int tid  = threadIdx.x;
    const int lane = tid & 63;
    const int wid  = tid >> 6;       // 0..7
    const int l15  = lane & 15;
    const int lg   = lane >> 4;
    const int nseg = T / (BM * NTILE);
    const int b    = blockIdx.x / (2 * nseg);
    const int rem  = blockIdx.x % (2 * nseg);
    const int dh   = rem / nseg;
    const int tb   = (rem % nseg) * (BM * NTILE);
    const int wm   = wid >> 2;       // 32-row half
    const int wd   = wid & 3;        // 32-col span within dh

    // ---- B fragments from global (pre-permuted layout), ONCE ----
    bf16x8 breg0[8], breg1[8];
    {
        const char* gB = (const char*)encT + ((size_t)b << 17) + ((size_t)dh << 16);
        const char* r0 = gB + (size_t)(wd * 32 + l15) * 512;
        const char* r1 = r0 + 16 * 512;
        #pragma unroll
        for (int ks = 0; ks < 8; ++ks) {
            const int koff = (2 * (ks * 32 + lg * 8)) ^ (l15 << 4);
            breg0[ks] = *(const bf16x8*)(r0 + koff);
            breg1[ks] = *(const bf16x8*)(r1 + koff);
        }
    }

    // ---- per-wave scan (8 waves redundant; identical-value race benign) ----
    {
        f32x4 dv = *(const f32x4*)(dur + b * S_FIX + 4 * lane);
        f32x4 rg = *(const f32x4*)(rng + b * S_FIX + 4 * lane);
        float q0 = dv[0];
        float q1 = q0 + dv[1];
        float q2 = q1 + dv[2];
        float q3 = q2 + dv[3];
        float tot = q3;
        #pragma unroll
        for (int off = 1; off < 64; off <<= 1) {
            float n = __shfl_up(tot, off, 64);
            if (lane >= off) tot += n;
        }
        float excl = __shfl_up(tot, 1, 64);
        if (lane == 0) excl = 0.0f;
        f32x4 c4, n4;
        c4[0] = excl + q0 - 0.5f * dv[0];
        c4[1] = excl + q1 - 0.5f * dv[1];
        c4[2] = excl + q2 - 0.5f * dv[2];
        c4[3] = excl + q3 - 0.5f * dv[3];
        #pragma unroll
        for (int i = 0; i < 4; ++i) n4[i] = -1.0f / (rg[i] * rg[i]);
        *(f32x4*)(s_c   + 4 * lane) = c4;
        *(f32x4*)(s_nir + 4 * lane) = n4;
    }
    asm volatile("s_waitcnt lgkmcnt(0)" ::: "memory");   // own writes visible

    // ---- hoisted epilogue constants ----
    const float kf  = -logf(10000.0f) / (float)D_FIX;
    const int   de0 = dh * 128 + wd * 32 + l15;          // d for n=0
    const int   de1 = de0 + 16;                          // d for n=1
    const float fr0 = __expf(kf * (float)(de0 & ~1));
    const float fr1 = __expf(kf * (float)(de1 & ~1));
    const bool  odd = (l15 & 1);

    // ---- exp-tile generator: thread = (row r, k-slice kc=wid); b128 writes ----
    auto exp_tile = [&](int t0e, int buf) {
        const int r  = tid & 63;
        const int kc = tid >> 6;                  // == wid
        const float tt = (float)(t0e + r);
        const int swz = (r & 15) << 4;
        char* arow = (char*)s_A[buf] + (size_t)r * 512;
        float ps = 0.0f;
        #pragma unroll
        for (int c8 = 0; c8 < 4; ++c8) {          // 8 k per chunk -> one b128
            i32x4 pk;
            #pragma unroll
            for (int jj = 0; jj < 4; ++jj) {
                const int k = kc * 32 + c8 * 8 + 2 * jj;
                float2 cc = *(const float2*)(s_c + k);
                float2 nn = *(const float2*)(s_nir + k);
                float e0 = tt - cc.x, e1 = tt - cc.y;
                unsigned p = pack_bf2(__expf(nn.x * e0 * e0), __expf(nn.y * e1 * e1));
                pk[jj] = (int)p;
                ps += __uint_as_float(p << 16) + __uint_as_float(p & 0xFFFF0000u);
            }
            *(i32x4*)(arow + ((kc * 64 + c8 * 16) ^ swz)) = pk;
        }
        s_part[buf][kc][r] = ps;
    };

    f32x4 acc[2][2];

    // ---- epilogue: direct stores from acc (MFMA layout), PE inline ----
    auto store_tile = [&](int t0r, int pb) {
        #pragma unroll
        for (int m = 0; m < 2; ++m) {
            #pragma unroll
            for (int r = 0; r < 4; ++r) {
                const int row = wm * 32 + m * 16 + lg * 4 + r;
                const float iv = s_winv[pb][row];
                const float tt = (float)(t0r + row);
                float* orow = out + ((size_t)b * T + t0r + row) * D_FIX;
                const float a0 = tt * fr0;
                const float a1 = tt * fr1;
                orow[de0] = acc[m][0][r] * iv + (odd ? __cosf(a0) : __sinf(a0));
                orow[de1] = acc[m][1][r] * iv + (odd ? __cosf(a1) : __sinf(a1));
            }
        }
    };

    // ---- prologue: exp(0) ----
    exp_tile(tb, 0);
    asm volatile("s_waitcnt lgkmcnt(0)" ::: "memory");
    __builtin_amdgcn_s_barrier();
    asm volatile("" ::: "memory");

    // ---- pipelined tile loop: ONE barrier per tile ----
    #pragma unroll
    for (int tile = 0; tile < NTILE; ++tile) {
        const int cur = tile & 1;

        // winv(tile) -> s_winv[cur] (consumed by epilogue(tile) next phase)
        if (tid < BM) {
            float w2 = 1e-20f;
            #pragma unroll
            for (int kc = 0; kc < 8; ++kc) w2 += s_part[cur][kc][tid];
            s_winv[cur][tid] = 1.0f / w2;
        }

        // epilogue(tile-1): uses prior acc + s_winv[cur^1] (published last phase)
        if (tile > 0) store_tile(tb + (tile - 1) * BM, cur ^ 1);

        // kloop(tile): A from LDS (2 b128/step), B from registers
        #pragma unroll
        for (int m = 0; m < 2; ++m)
            #pragma unroll
            for (int n = 0; n < 2; ++n) acc[m][n] = (f32x4){0.f, 0.f, 0.f, 0.f};
        {
            const char* aB0 = (const char*)s_A[cur] + (size_t)(wm * 32 + l15) * 512;
            const char* aB1 = aB0 + 16 * 512;
            #pragma unroll
            for (int ks = 0; ks < 8; ++ks) {
                const int koff = (2 * (ks * 32 + lg * 8)) ^ (l15 << 4);
                bf16x8 a0 = *(const bf16x8*)(aB0 + koff);
                bf16x8 a1 = *(const bf16x8*)(aB1 + koff);
                acc[0][0] = __builtin_amdgcn_mfma_f32_16x16x32_bf16(a0, breg0[ks], acc[0][0], 0, 0, 0);
                acc[0][1] = __builtin_amdgcn_mfma_f32_16x16x32_bf16(a0, breg1[ks], acc[0][1], 0, 0, 0);
                acc[1][0] = __builtin_amdgcn_mfma_f32_16x16x32_bf16(a1, breg0[ks], acc[1][0], 0, 0, 0);
                acc[1][1] = __builtin_amdgcn_mfma_f32_16x16x32_bf16(a1, breg1[ks], acc[1][1], 0, 0, 0);
            }
        }

        // exp(tile+1) -> A[cur^1] (overwrites buffer whose reads finished @ bar(tile-1))
        if (tile + 1 < NTILE) exp_tile(tb + (tile + 1) * BM, cur ^ 1);

        asm volatile("s_waitcnt lgkmcnt(0)" ::: "memory");
        __builtin_amdgcn_s_barrier();
        asm volatile("" ::: "memory");
    }

    // ---- final epilogue (winv published before last barrier) ----
    store_tile(tb + (NTILE - 1) * BM, (NTILE - 1) & 1);
}

// ---------------- fallback (round-1 f32 kernel) ----------------
#define FBM 32
#define BLOCK 256
__global__ __launch_bounds__(BLOCK) void gauss_up_f32(
    const float* __restrict__ enc, const float* __restrict__ dur,
    const float* __restrict__ rng, float* __restrict__ out,
    int T, int D, int ntiles)
{
    __shared__ float s_w[FBM][S_FIX];
    __shared__ float s_c[S_FIX];
    __shared__ float s_ir2[S_FIX];
    __shared__ float s_scan[S_FIX];
    __shared__ float s_part[8][FBM];
    __shared__ float s_winv[FBM];

    const int tid = threadIdx.x;
    const int b   = blockIdx.x / ntiles;
    const int t0  = (blockIdx.x % ntiles) * FBM;

    float dv = dur[b * S_FIX + tid];
    s_scan[tid] = dv;
    __syncthreads();
    #pragma unroll
    for (int off = 1; off < S_FIX; off <<= 1) {
        float cur = s_scan[tid];
        float add = (tid >= off) ? s_scan[tid - off] : 0.0f;
        __syncthreads();
        s_scan[tid] = cur + add;
        __syncthreads();
    }
    {
        float e = s_scan[tid];
        float c = e - 0.5f * dv;
        float r = rng[b * S_FIX + tid];
        s_c[tid] = c; s_ir2[tid] = 1.0f / (r * r);
    }
    __syncthreads();
    {
        float cc = s_c[tid], ir = s_ir2[tid];
        #pragma unroll 4
        for (int tl = 0; tl < FBM; ++tl) {
            float tt = (float)(t0 + tl);
            float df = tt - cc;
            s_w[tl][tid] = __expf(-ir * df * df);
        }
    }
    __syncthreads();
    {
        const int t = tid & 31, ch = tid >> 5;
        float ps = 0.0f;
        #pragma unroll 8
        for (int j = 0; j < 32; ++j) ps += s_w[t][ch * 32 + ((j + t) & 31)];
        s_part[ch][t] = ps;
    }
    __syncthreads();
    if (tid < FBM) {
        float w2 = s_part[0][tid] + s_part[1][tid] + s_part[2][tid] + s_part[3][tid]
                 + s_part[4][tid] + s_part[5][tid] + s_part[6][tid] + s_part[7][tid] + 1e-20f;
        s_winv[tid] = 1.0f / w2;
    }
    __syncthreads();

    const int dq = tid & 63, tg = tid >> 6;
    float4 acc[8];
    #pragma unroll
    for (int i = 0; i < 8; ++i) acc[i] = make_float4(0.f, 0.f, 0.f, 0.f);
    const float* encb = enc + (size_t)b * S_FIX * D + (size_t)dq * 4;
    #pragma unroll 4
    for (int s = 0; s < S_FIX; ++s) {
        float4 ev = *(const float4*)(encb + (size_t)s * D);
        #pragma unroll
        for (int i = 0; i < 8; ++i) {
            float wv = s_w[tg * 8 + i][s];
            acc[i].x = fmaf(wv, ev.x, acc[i].x);
            acc[i].y = fmaf(wv, ev.y, acc[i].y);
            acc[i].z = fmaf(wv, ev.z, acc[i].z);
            acc[i].w = fmaf(wv, ev.w, acc[i].w);
        }
    }
    const float kf = -logf(10000.0f) / (float)D;
    const int d0 = dq * 4;
    const float f0 = __expf(kf * (float)(d0));
    const float f2 = __expf(kf * (float)(d0 + 2));
    float* outb = out + (size_t)b * T * D + (size_t)t0 * D + d0;
    #pragma unroll
    for (int i = 0; i < 8; ++i) {
        const int tl = tg * 8 + i;
        const float inv = s_winv[tl];
        const float tt = (float)(t0 + tl);
        const float a0 = tt * f0, a2 = tt * f2;
        float4 o;
        o.x = acc[i].x * inv + __sinf(a0);
        o.y = acc[i].y * inv + __cosf(a0);
        o.z = acc[i].z * inv + __sinf(a2);
        o.w = acc[i].w * inv + __cosf(a2);
        *(float4*)(outb + (size_t)tl * D) = o;
    }
}

extern "C" void kernel_launch(void* const* d_in, const int* in_sizes, int n_in,
                              void* d_out, int out_size, void* d_ws, size_t ws_size,
                              hipStream_t stream) {
    const float* enc = (const float*)d_in[0];
    const float* dur = (const float*)d_in[1];
    const float* rng = (const float*)d_in[2];
    float* out = (float*)d_out;

    const int S  = S_FIX;
    const int BS = in_sizes[1];
    const int B  = BS / S;
    const int D  = in_sizes[0] / BS;
    const int T  = out_size / (B * D);

    const size_t need = (size_t)B * D * S * sizeof(unsigned short);  // 4 MB

    if (D == D_FIX && S == S_FIX && (T % (BM * NTILE)) == 0 && ws_size >= need) {
        unsigned short* encT = (unsigned short*)d_ws;
        hipLaunchKernelGGL(transpose_enc_bf16, dim3(B * (S / 8) * D / 256), dim3(256),
                           0, stream, enc, encT);
        const int grid = B * 2 * (T / (BM * NTILE));   // 32*2*8 = 512
        hipLaunchKernelGGL(gauss_fused2, dim3(grid), dim3(512), 0, stream,
                           dur, rng, encT, out, T);
    } else {
        const int ntiles = T / FBM;
        hipLaunchKernelGGL(gauss_up_f32, dim3(B * ntiles), dim3(BLOCK), 0, stream,
                           enc, dur, rng, out, T, D, ntiles);
    }
}

// Round 12
// 41.027 us; speedup vs baseline: 1.0098x; 1.0098x over previous
//
#include <hip/hip_runtime.h>
#include <hip/hip_bf16.h>
#include <math.h>

// Gaussian upsampling, round 12: R10 structure + B-in-regs + b128 exp + raw barriers.
//   K0 transpose_enc_bf16 : enc -> pre-permuted encT (validated R10/R11)
//   K1 gauss_fused3       : grid 512 (2/CU), 512 thr (8 waves). Block = (b, dh,
//                           256 rows = 4 tiles of 64).
//     - B-frags (16 x bf16x8) in VGPRs, loaded once from pre-permuted global
//     - per tile: {winv | kloop(A from LDS, B regs)} bar {epilogue R10-style
//       LDS-transpose f32x4 stores | exp(t+1) b128 -> s_A} bar
//     - raw s_barrier + lgkmcnt(0) only (no vmcnt drain; stores write-once)

typedef short  bf16x8 __attribute__((ext_vector_type(8)));
typedef float  f32x4  __attribute__((ext_vector_type(4)));
typedef int    i32x4  __attribute__((ext_vector_type(4)));
typedef unsigned short u16x8 __attribute__((ext_vector_type(8)));

#define S_FIX 256
#define D_FIX 256
#define BM    64      // t-rows per tile
#define NTILE 4       // tiles per block (256 rows)
#define STG   40      // epilogue staging stride (floats)

static __device__ __forceinline__ unsigned short f2bf(float f) {
    union { float f; unsigned u; } v; v.f = f;
    unsigned r = v.u + 0x7FFFu + ((v.u >> 16) & 1u);   // RNE
    return (unsigned short)(r >> 16);
}

static __device__ __forceinline__ unsigned pack_bf2(float lo, float hi) {
    float2 v; v.x = lo; v.y = hi;
    union { __hip_bfloat162 h; unsigned u; } c;
    c.h = __float22bfloat162_rn(v);
    return c.u;   // low16 = bf16(lo), high16 = bf16(hi)
}

// ---------------- K0: enc -> encT (pre-permuted; validated) ----------------
__global__ __launch_bounds__(256) void transpose_enc_bf16(
    const float* __restrict__ enc, unsigned short* __restrict__ encT)
{
    const int g  = blockIdx.x * 256 + threadIdx.x;
    const int d  = g & 255;
    const int sc = (g >> 8) & 31;     // 8-s chunk
    const int b  = g >> 13;
    const int s0 = sc * 8;
    const float* p = enc + ((size_t)b << 16) + (size_t)s0 * D_FIX + d;
    u16x8 v;
    #pragma unroll
    for (int j = 0; j < 8; ++j) v[j] = f2bf(p[(size_t)j * D_FIX]);
    const int dh = d >> 7, dl = d & 127;
    const size_t off = ((size_t)b << 17) + ((size_t)dh << 16)
                     + (size_t)dl * 512 + (unsigned)((16 * sc) ^ ((dl & 15) << 4));
    *(u16x8*)((char*)encT + off) = v;
}

// ---------------- K1: fused main ----------------
__global__ __launch_bounds__(512) void gauss_fused3(
    const float* __restrict__ dur,            // (B,S)
    const float* __restrict__ rng,            // (B,S,1)
    const unsigned short* __restrict__ encT,  // permuted (B,2,128,256)
    float* __restrict__ out,                  // (B,T,D)
    int T)
{
    __shared__ __align__(16) short s_A[BM * S_FIX];      // 32 KB
    __shared__ __align__(16) float s_stg[8][16 * STG];   // 20 KB
    __shared__ float s_c[S_FIX];
    __shared__ float s_nir[S_FIX];
    __shared__ float s_part[8][BM];
    __shared__ float s_winv[BM];

    const int tid  = threadIdx.x;
    const int lane = tid & 63;
    const int wid  = tid >> 6;       // 0..7
    const int l15  = lane & 15;
    const int lg   = lane >> 4;
    const int nseg = T / (BM * NTILE);
    const int b    = blockIdx.x / (2 * nseg);
    const int rem  = blockIdx.x % (2 * nseg);
    const int dh   = rem / nseg;
    const int tb   = (rem % nseg) * (BM * NTILE);
    const int wm   = wid >> 2;       // 32-row half
    const int wd   = wid & 3;        // 32-col span within dh

    // ---- B fragments from global (pre-permuted layout), ONCE ----
    bf16x8 breg0[8], breg1[8];
    {
        const char* gB = (const char*)encT + ((size_t)b << 17) + ((size_t)dh << 16);
        const char* r0 = gB + (size_t)(wd * 32 + l15) * 512;
        const char* r1 = r0 + 16 * 512;
        #pragma unroll
        for (int ks = 0; ks < 8; ++ks) {
            const int koff = (2 * (ks * 32 + lg * 8)) ^ (l15 << 4);
            breg0[ks] = *(const bf16x8*)(r0 + koff);
            breg1[ks] = *(const bf16x8*)(r1 + koff);
        }
    }

    // ---- per-wave scan (8 waves redundant; identical-value race benign) ----
    {
        f32x4 dv = *(const f32x4*)(dur + b * S_FIX + 4 * lane);
        f32x4 rg = *(const f32x4*)(rng + b * S_FIX + 4 * lane);
        float q0 = dv[0];
        float q1 = q0 + dv[1];
        float q2 = q1 + dv[2];
        float q3 = q2 + dv[3];
        float tot = q3;
        #pragma unroll
        for (int off = 1; off < 64; off <<= 1) {
            float n = __shfl_up(tot, off, 64);
            if (lane >= off) tot += n;
        }
        float excl = __shfl_up(tot, 1, 64);
        if (lane == 0) excl = 0.0f;
        f32x4 c4, n4;
        c4[0] = excl + q0 - 0.5f * dv[0];
        c4[1] = excl + q1 - 0.5f * dv[1];
        c4[2] = excl + q2 - 0.5f * dv[2];
        c4[3] = excl + q3 - 0.5f * dv[3];
        #pragma unroll
        for (int i = 0; i < 4; ++i) n4[i] = -1.0f / (rg[i] * rg[i]);
        *(f32x4*)(s_c   + 4 * lane) = c4;
        *(f32x4*)(s_nir + 4 * lane) = n4;
    }
    asm volatile("s_waitcnt lgkmcnt(0)" ::: "memory");   // own writes visible

    // ---- hoisted epilogue constants (R10 mapping) ----
    const int q8 = lane & 7;                             // f32x4 quad in 32-col span
    const int dq = dh * 128 + wd * 32 + 4 * q8;          // absolute d (mult of 4)
    const float kf = -logf(10000.0f) / (float)D_FIX;
    const float f0 = __expf(kf * (float)dq);
    const float f2 = __expf(kf * (float)(dq + 2));

    // ---- exp-tile generator (b128 writes, validated R11) ----
    auto exp_tile = [&](int t0e) {
        const int r  = tid & 63;
        const int kc = tid >> 6;                  // == wid
        const float tt = (float)(t0e + r);
        const int swz = (r & 15) << 4;
        char* arow = (char*)s_A + (size_t)r * 512;
        float ps = 0.0f;
        #pragma unroll
        for (int c8 = 0; c8 < 4; ++c8) {          // 8 k per chunk -> one b128
            i32x4 pk;
            #pragma unroll
            for (int jj = 0; jj < 4; ++jj) {
                const int k = kc * 32 + c8 * 8 + 2 * jj;
                float2 cc = *(const float2*)(s_c + k);
                float2 nn = *(const float2*)(s_nir + k);
                float e0 = tt - cc.x, e1 = tt - cc.y;
                unsigned p = pack_bf2(__expf(nn.x * e0 * e0), __expf(nn.y * e1 * e1));
                pk[jj] = (int)p;
                ps += __uint_as_float(p << 16) + __uint_as_float(p & 0xFFFF0000u);
            }
            *(i32x4*)(arow + ((kc * 64 + c8 * 16) ^ swz)) = pk;
        }
        s_part[kc][r] = ps;
    };

    // ---- prologue: exp(0) ----
    exp_tile(tb);
    asm volatile("s_waitcnt lgkmcnt(0)" ::: "memory");
    __builtin_amdgcn_s_barrier();
    asm volatile("" ::: "memory");

    f32x4 acc[2][2];

    for (int tile = 0; tile < NTILE; ++tile) {
        const int t0 = tb + tile * BM;

        // winv(tile)
        if (tid < BM) {
            float w2 = 1e-20f;
            #pragma unroll
            for (int kc = 0; kc < 8; ++kc) w2 += s_part[kc][tid];
            s_winv[tid] = 1.0f / w2;
        }

        // kloop: A from LDS, B from registers
        #pragma unroll
        for (int m = 0; m < 2; ++m)
            #pragma unroll
            for (int n = 0; n < 2; ++n) acc[m][n] = (f32x4){0.f, 0.f, 0.f, 0.f};
        {
            const char* aB0 = (const char*)s_A + (size_t)(wm * 32 + l15) * 512;
            const char* aB1 = aB0 + 16 * 512;
            #pragma unroll
            for (int ks = 0; ks < 8; ++ks) {
                const int koff = (2 * (ks * 32 + lg * 8)) ^ (l15 << 4);
                bf16x8 a0 = *(const bf16x8*)(aB0 + koff);
                bf16x8 a1 = *(const bf16x8*)(aB1 + koff);
                acc[0][0] = __builtin_amdgcn_mfma_f32_16x16x32_bf16(a0, breg0[ks], acc[0][0], 0, 0, 0);
                acc[0][1] = __builtin_amdgcn_mfma_f32_16x16x32_bf16(a0, breg1[ks], acc[0][1], 0, 0, 0);
                acc[1][0] = __builtin_amdgcn_mfma_f32_16x16x32_bf16(a1, breg0[ks], acc[1][0], 0, 0, 0);
                acc[1][1] = __builtin_amdgcn_mfma_f32_16x16x32_bf16(a1, breg1[ks], acc[1][1], 0, 0, 0);
            }
        }

        // bar: kloop A-reads done; winv published
        asm volatile("s_waitcnt lgkmcnt(0)" ::: "memory");
        __builtin_amdgcn_s_barrier();
        asm volatile("" ::: "memory");

        // epilogue(tile): R10 LDS-transpose + f32x4 coalesced stores
        {
            float* stg = s_stg[wid];
            #pragma unroll
            for (int mi = 0; mi < 2; ++mi) {
                asm volatile("s_waitcnt lgkmcnt(0)" ::: "memory");  // WAR on stg
                #pragma unroll
                for (int ni = 0; ni < 2; ++ni)
                    #pragma unroll
                    for (int r = 0; r < 4; ++r)
                        stg[(lg * 4 + r) * STG + ni * 16 + l15] = acc[mi][ni][r];
                asm volatile("s_waitcnt lgkmcnt(0)" ::: "memory");
                const int rl = lane >> 3;        // 0..7
                #pragma unroll
                for (int h = 0; h < 2; ++h) {
                    const int rr = rl + 8 * h;                    // 0..15
                    const int tr = wm * 32 + mi * 16 + rr;        // row in tile
                    f32x4 v = *(const f32x4*)(stg + rr * STG + 4 * q8);
                    const float iv = s_winv[tr];
                    const float t  = (float)(t0 + tr);
                    float sa, ca, sb, cb;
                    __sincosf(t * f0, &sa, &ca);
                    __sincosf(t * f2, &sb, &cb);
                    v[0] = v[0] * iv + sa;
                    v[1] = v[1] * iv + ca;
                    v[2] = v[2] * iv + sb;
                    v[3] = v[3] * iv + cb;
                    *(f32x4*)(out + ((size_t)b * T + t0 + tr) * D_FIX + dq) = v;
                }
            }
        }

        // exp(tile+1) overwrites s_A (safe: A-reads drained at the bar above)
        if (tile + 1 < NTILE) {
            exp_tile(t0 + BM);
            asm volatile("s_waitcnt lgkmcnt(0)" ::: "memory");
            __builtin_amdgcn_s_barrier();
            asm volatile("" ::: "memory");
        }
    }
}

// ---------------- fallback (round-1 f32 kernel) ----------------
#define FBM 32
#define BLOCK 256
__global__ __launch_bounds__(BLOCK) void gauss_up_f32(
    const float* __restrict__ enc, const float* __restrict__ dur,
    const float* __restrict__ rng, float* __restrict__ out,
    int T, int D, int ntiles)
{
    __shared__ float s_w[FBM][S_FIX];
    __shared__ float s_c[S_FIX];
    __shared__ float s_ir2[S_FIX];
    __shared__ float s_scan[S_FIX];
    __shared__ float s_part[8][FBM];
    __shared__ float s_winv[FBM];

    const int tid = threadIdx.x;
    const int b   = blockIdx.x / ntiles;
    const int t0  = (blockIdx.x % ntiles) * FBM;

    float dv = dur[b * S_FIX + tid];
    s_scan[tid] = dv;
    __syncthreads();
    #pragma unroll
    for (int off = 1; off < S_FIX; off <<= 1) {
        float cur = s_scan[tid];
        float add = (tid >= off) ? s_scan[tid - off] : 0.0f;
        __syncthreads();
        s_scan[tid] = cur + add;
        __syncthreads();
    }
    {
        float e = s_scan[tid];
        float c = e - 0.5f * dv;
        float r = rng[b * S_FIX + tid];
        s_c[tid] = c; s_ir2[tid] = 1.0f / (r * r);
    }
    __syncthreads();
    {
        float cc = s_c[tid], ir = s_ir2[tid];
        #pragma unroll 4
        for (int tl = 0; tl < FBM; ++tl) {
            float tt = (float)(t0 + tl);
            float df = tt - cc;
            s_w[tl][tid] = __expf(-ir * df * df);
        }
    }
    __syncthreads();
    {
        const int t = tid & 31, ch = tid >> 5;
        float ps = 0.0f;
        #pragma unroll 8
        for (int j = 0; j < 32; ++j) ps += s_w[t][ch * 32 + ((j + t) & 31)];
        s_part[ch][t] = ps;
    }
    __syncthreads();
    if (tid < FBM) {
        float w2 = s_part[0][tid] + s_part[1][tid] + s_part[2][tid] + s_part[3][tid]
                 + s_part[4][tid] + s_part[5][tid] + s_part[6][tid] + s_part[7][tid] + 1e-20f;
        s_winv[tid] = 1.0f / w2;
    }
    __syncthreads();

    const int dq = tid & 63, tg = tid >> 6;
    float4 acc[8];
    #pragma unroll
    for (int i = 0; i < 8; ++i) acc[i] = make_float4(0.f, 0.f, 0.f, 0.f);
    const float* encb = enc + (size_t)b * S_FIX * D + (size_t)dq * 4;
    #pragma unroll 4
    for (int s = 0; s < S_FIX; ++s) {
        float4 ev = *(const float4*)(encb + (size_t)s * D);
        #pragma unroll
        for (int i = 0; i < 8; ++i) {
            float wv = s_w[tg * 8 + i][s];
            acc[i].x = fmaf(wv, ev.x, acc[i].x);
            acc[i].y = fmaf(wv, ev.y, acc[i].y);
            acc[i].z = fmaf(wv, ev.z, acc[i].z);
            acc[i].w = fmaf(wv, ev.w, acc[i].w);
        }
    }
    const float kf = -logf(10000.0f) / (float)D;
    const int d0 = dq * 4;
    const float f0 = __expf(kf * (float)(d0));
    const float f2 = __expf(kf * (float)(d0 + 2));
    float* outb = out + (size_t)b * T * D + (size_t)t0 * D + d0;
    #pragma unroll
    for (int i = 0; i < 8; ++i) {
        const int tl = tg * 8 + i;
        const float inv = s_winv[tl];
        const float tt = (float)(t0 + tl);
        const float a0 = tt * f0, a2 = tt * f2;
        float4 o;
        o.x = acc[i].x * inv + __sinf(a0);
        o.y = acc[i].y * inv + __cosf(a0);
        o.z = acc[i].z * inv + __sinf(a2);
        o.w = acc[i].w * inv + __cosf(a2);
        *(float4*)(outb + (size_t)tl * D) = o;
    }
}

extern "C" void kernel_launch(void* const* d_in, const int* in_sizes, int n_in,
                              void* d_out, int out_size, void* d_ws, size_t ws_size,
                              hipStream_t stream) {
    const float* enc = (const float*)d_in[0];
    const float* dur = (const float*)d_in[1];
    const float* rng = (const float*)d_in[2];
    float* out = (float*)d_out;

    const int S  = S_FIX;
    const int BS = in_sizes[1];
    const int B  = BS / S;
    const int D  = in_sizes[0] / BS;
    const int T  = out_size / (B * D);

    const size_t need = (size_t)B * D * S * sizeof(unsigned short);  // 4 MB

    if (D == D_FIX && S == S_FIX && (T % (BM * NTILE)) == 0 && ws_size >= need) {
        unsigned short* encT = (unsigned short*)d_ws;
        hipLaunchKernelGGL(transpose_enc_bf16, dim3(B * (S / 8) * D / 256), dim3(256),
                           0, stream, enc, encT);
        const int grid = B * 2 * (T / (BM * NTILE));   // 32*2*8 = 512
        hipLaunchKernelGGL(gauss_fused3, dim3(grid), dim3(512), 0, stream,
                           dur, rng, encT, out, T);
    } else {
        const int ntiles = T / FBM;
        hipLaunchKernelGGL(gauss_up_f32, dim3(B * ntiles), dim3(BLOCK), 0, stream,
                           enc, dur, rng, out, T, D, ntiles);
    }
}

// Round 13
// 33.658 us; speedup vs baseline: 1.2308x; 1.2189x over previous
//
#include <hip/hip_runtime.h>
#include <hip/hip_bf16.h>
#include <math.h>

// Gaussian upsampling, round 13: full-D blocks — exp computed ONCE per (b,t).
//   K0 transpose_enc_bf16 : enc -> pre-permuted encT (validated)
//   K1 gauss_fused4       : grid 256 (1/CU), 512 thr (8 waves). Block = (b, 256
//                           t-rows = 4 tiles of 64). Wave wid owns d-span
//                           [wid*32, wid*32+32) -> 8 waves cover ALL 256 d.
//     - B-frags (16 x bf16x8/wave) in VGPRs from pre-permuted global, once
//     - per tile: {winv | kloop: 4 A b128 from LDS + 8 MFMA per ks} bar
//                 {epilogue: stg-transpose + f32x4 stores | exp(t+1) b128} bar
//     - A-tile computed once (no dh duplication): exp work halved vs R10/R12

typedef short  bf16x8 __attribute__((ext_vector_type(8)));
typedef float  f32x4  __attribute__((ext_vector_type(4)));
typedef int    i32x4  __attribute__((ext_vector_type(4)));
typedef unsigned short u16x8 __attribute__((ext_vector_type(8)));

#define S_FIX 256
#define D_FIX 256
#define BM    64      // t-rows per tile
#define NTILE 4       // tiles per block (256 rows)
#define STG   40      // epilogue staging stride (floats)

static __device__ __forceinline__ unsigned short f2bf(float f) {
    union { float f; unsigned u; } v; v.f = f;
    unsigned r = v.u + 0x7FFFu + ((v.u >> 16) & 1u);   // RNE
    return (unsigned short)(r >> 16);
}

static __device__ __forceinline__ unsigned pack_bf2(float lo, float hi) {
    float2 v; v.x = lo; v.y = hi;
    union { __hip_bfloat162 h; unsigned u; } c;
    c.h = __float22bfloat162_rn(v);
    return c.u;   // low16 = bf16(lo), high16 = bf16(hi)
}

// ---------------- K0: enc -> encT (pre-permuted; validated) ----------------
__global__ __launch_bounds__(256) void transpose_enc_bf16(
    const float* __restrict__ enc, unsigned short* __restrict__ encT)
{
    const int g  = blockIdx.x * 256 + threadIdx.x;
    const int d  = g & 255;
    const int sc = (g >> 8) & 31;     // 8-s chunk
    const int b  = g >> 13;
    const int s0 = sc * 8;
    const float* p = enc + ((size_t)b << 16) + (size_t)s0 * D_FIX + d;
    u16x8 v;
    #pragma unroll
    for (int j = 0; j < 8; ++j) v[j] = f2bf(p[(size_t)j * D_FIX]);
    const int dh = d >> 7, dl = d & 127;
    const size_t off = ((size_t)b << 17) + ((size_t)dh << 16)
                     + (size_t)dl * 512 + (unsigned)((16 * sc) ^ ((dl & 15) << 4));
    *(u16x8*)((char*)encT + off) = v;
}

// ---------------- K1: fused main (full-D) ----------------
__global__ __launch_bounds__(512) void gauss_fused4(
    const float* __restrict__ dur,            // (B,S)
    const float* __restrict__ rng,            // (B,S,1)
    const unsigned short* __restrict__ encT,  // permuted (B,2,128,256)
    float* __restrict__ out,                  // (B,T,D)
    int T)
{
    __shared__ __align__(16) short s_A[BM * S_FIX];      // 32 KB
    __shared__ __align__(16) float s_stg[8][16 * STG];   // 20 KB
    __shared__ float s_c[S_FIX];
    __shared__ float s_nir[S_FIX];
    __shared__ float s_part[8][BM];
    __shared__ float s_winv[BM];

    const int tid  = threadIdx.x;
    const int lane = tid & 63;
    const int wid  = tid >> 6;       // 0..7 -> d-span wid*32
    const int l15  = lane & 15;
    const int lg   = lane >> 4;
    const int nseg = T / (BM * NTILE);            // 8
    const int b    = blockIdx.x / nseg;
    const int tb   = (blockIdx.x % nseg) * (BM * NTILE);
    const int dhw  = wid >> 2;       // which 128-half this wave's span lives in
    const int wdl  = wid & 3;        // 32-col span within the half

    // ---- B fragments from global (pre-permuted layout), ONCE ----
    bf16x8 breg0[8], breg1[8];       // cols wid*32 + {0..15}, {16..31}
    {
        const char* gB = (const char*)encT + ((size_t)b << 17) + ((size_t)dhw << 16);
        const char* r0 = gB + (size_t)(wdl * 32 + l15) * 512;
        const char* r1 = r0 + 16 * 512;
        #pragma unroll
        for (int ks = 0; ks < 8; ++ks) {
            const int koff = (2 * (ks * 32 + lg * 8)) ^ (l15 << 4);
            breg0[ks] = *(const bf16x8*)(r0 + koff);
            breg1[ks] = *(const bf16x8*)(r1 + koff);
        }
    }

    // ---- per-wave scan (8 waves redundant; identical-value race benign) ----
    {
        f32x4 dv = *(const f32x4*)(dur + b * S_FIX + 4 * lane);
        f32x4 rg = *(const f32x4*)(rng + b * S_FIX + 4 * lane);
        float q0 = dv[0];
        float q1 = q0 + dv[1];
        float q2 = q1 + dv[2];
        float q3 = q2 + dv[3];
        float tot = q3;
        #pragma unroll
        for (int off = 1; off < 64; off <<= 1) {
            float n = __shfl_up(tot, off, 64);
            if (lane >= off) tot += n;
        }
        float excl = __shfl_up(tot, 1, 64);
        if (lane == 0) excl = 0.0f;
        f32x4 c4, n4;
        c4[0] = excl + q0 - 0.5f * dv[0];
        c4[1] = excl + q1 - 0.5f * dv[1];
        c4[2] = excl + q2 - 0.5f * dv[2];
        c4[3] = excl + q3 - 0.5f * dv[3];
        #pragma unroll
        for (int i = 0; i < 4; ++i) n4[i] = -1.0f / (rg[i] * rg[i]);
        *(f32x4*)(s_c   + 4 * lane) = c4;
        *(f32x4*)(s_nir + 4 * lane) = n4;
    }
    asm volatile("s_waitcnt lgkmcnt(0)" ::: "memory");   // own writes visible

    // ---- hoisted epilogue constants ----
    const int q8 = lane & 7;                           // f32x4 quad in 32-col span
    const int dq = wid * 32 + 4 * q8;                  // absolute d (mult of 4)
    const float kf = -logf(10000.0f) / (float)D_FIX;
    const float f0 = __expf(kf * (float)dq);
    const float f2 = __expf(kf * (float)(dq + 2));

    // ---- exp-tile generator (b128 writes; computed ONCE per (b,tile)) ----
    auto exp_tile = [&](int t0e) {
        const int r  = tid & 63;
        const int kc = tid >> 6;                  // == wid
        const float tt = (float)(t0e + r);
        const int swz = (r & 15) << 4;
        char* arow = (char*)s_A + (size_t)r * 512;
        float ps = 0.0f;
        #pragma unroll
        for (int c8 = 0; c8 < 4; ++c8) {          // 8 k per chunk -> one b128
            i32x4 pk;
            #pragma unroll
            for (int jj = 0; jj < 4; ++jj) {
                const int k = kc * 32 + c8 * 8 + 2 * jj;
                float2 cc = *(const float2*)(s_c + k);
                float2 nn = *(const float2*)(s_nir + k);
                float e0 = tt - cc.x, e1 = tt - cc.y;
                unsigned p = pack_bf2(__expf(nn.x * e0 * e0), __expf(nn.y * e1 * e1));
                pk[jj] = (int)p;
                ps += __uint_as_float(p << 16) + __uint_as_float(p & 0xFFFF0000u);
            }
            *(i32x4*)(arow + ((kc * 64 + c8 * 16) ^ swz)) = pk;
        }
        s_part[kc][r] = ps;
    };

    // ---- prologue: exp(0) ----
    exp_tile(tb);
    asm volatile("s_waitcnt lgkmcnt(0)" ::: "memory");
    __builtin_amdgcn_s_barrier();
    asm volatile("" ::: "memory");

    f32x4 acc[4][2];

    for (int tile = 0; tile < NTILE; ++tile) {
        const int t0 = tb + tile * BM;

        // winv(tile)
        if (tid < BM) {
            float w2 = 1e-20f;
            #pragma unroll
            for (int kc = 0; kc < 8; ++kc) w2 += s_part[kc][tid];
            s_winv[tid] = 1.0f / w2;
        }

        // kloop: 4 A-frags (rows m*16+l15) from LDS, B from registers, 8 MFMA/ks
        #pragma unroll
        for (int m = 0; m < 4; ++m)
            #pragma unroll
            for (int n = 0; n < 2; ++n) acc[m][n] = (f32x4){0.f, 0.f, 0.f, 0.f};
        {
            const char* aB = (const char*)s_A + (size_t)l15 * 512;
            #pragma unroll
            for (int ks = 0; ks < 8; ++ks) {
                const int koff = (2 * (ks * 32 + lg * 8)) ^ (l15 << 4);
                bf16x8 a0 = *(const bf16x8*)(aB + koff);
                bf16x8 a1 = *(const bf16x8*)(aB + 8192  + koff);
                bf16x8 a2 = *(const bf16x8*)(aB + 16384 + koff);
                bf16x8 a3 = *(const bf16x8*)(aB + 24576 + koff);
                acc[0][0] = __builtin_amdgcn_mfma_f32_16x16x32_bf16(a0, breg0[ks], acc[0][0], 0, 0, 0);
                acc[0][1] = __builtin_amdgcn_mfma_f32_16x16x32_bf16(a0, breg1[ks], acc[0][1], 0, 0, 0);
                acc[1][0] = __builtin_amdgcn_mfma_f32_16x16x32_bf16(a1, breg0[ks], acc[1][0], 0, 0, 0);
                acc[1][1] = __builtin_amdgcn_mfma_f32_16x16x32_bf16(a1, breg1[ks], acc[1][1], 0, 0, 0);
                acc[2][0] = __builtin_amdgcn_mfma_f32_16x16x32_bf16(a2, breg0[ks], acc[2][0], 0, 0, 0);
                acc[2][1] = __builtin_amdgcn_mfma_f32_16x16x32_bf16(a2, breg1[ks], acc[2][1], 0, 0, 0);
                acc[3][0] = __builtin_amdgcn_mfma_f32_16x16x32_bf16(a3, breg0[ks], acc[3][0], 0, 0, 0);
                acc[3][1] = __builtin_amdgcn_mfma_f32_16x16x32_bf16(a3, breg1[ks], acc[3][1], 0, 0, 0);
            }
        }

        // bar: kloop A-reads done; winv published
        asm volatile("s_waitcnt lgkmcnt(0)" ::: "memory");
        __builtin_amdgcn_s_barrier();
        asm volatile("" ::: "memory");

        // epilogue(tile): per-m stg transpose + f32x4 coalesced stores
        {
            float* stg = s_stg[wid];
            #pragma unroll
            for (int m = 0; m < 4; ++m) {
                asm volatile("s_waitcnt lgkmcnt(0)" ::: "memory");  // WAR on stg
                #pragma unroll
                for (int n = 0; n < 2; ++n)
                    #pragma unroll
                    for (int r = 0; r < 4; ++r)
                        stg[(lg * 4 + r) * STG + n * 16 + l15] = acc[m][n][r];
                asm volatile("s_waitcnt lgkmcnt(0)" ::: "memory");
                const int rl = lane >> 3;        // 0..7
                #pragma unroll
                for (int h = 0; h < 2; ++h) {
                    const int rr = rl + 8 * h;                 // 0..15
                    const int tr = m * 16 + rr;                // row in tile 0..63
                    f32x4 v = *(const f32x4*)(stg + rr * STG + 4 * q8);
                    const float iv = s_winv[tr];
                    const float t  = (float)(t0 + tr);
                    float sa, ca, sb, cb;
                    __sincosf(t * f0, &sa, &ca);
                    __sincosf(t * f2, &sb, &cb);
                    v[0] = v[0] * iv + sa;
                    v[1] = v[1] * iv + ca;
                    v[2] = v[2] * iv + sb;
                    v[3] = v[3] * iv + cb;
                    *(f32x4*)(out + ((size_t)b * T + t0 + tr) * D_FIX + dq) = v;
                }
            }
        }

        // exp(tile+1) overwrites s_A (A-reads drained at the bar above);
        // stores above remain in flight -> latency hides under this VALU work
        if (tile + 1 < NTILE) {
            exp_tile(t0 + BM);
            asm volatile("s_waitcnt lgkmcnt(0)" ::: "memory");
            __builtin_amdgcn_s_barrier();
            asm volatile("" ::: "memory");
        }
    }
}

// ---------------- fallback (round-1 f32 kernel) ----------------
#define FBM 32
#define BLOCK 256
__global__ __launch_bounds__(BLOCK) void gauss_up_f32(
    const float* __restrict__ enc, const float* __restrict__ dur,
    const float* __restrict__ rng, float* __restrict__ out,
    int T, int D, int ntiles)
{
    __shared__ float s_w[FBM][S_FIX];
    __shared__ float s_c[S_FIX];
    __shared__ float s_ir2[S_FIX];
    __shared__ float s_scan[S_FIX];
    __shared__ float s_part[8][FBM];
    __shared__ float s_winv[FBM];

    const int tid = threadIdx.x;
    const int b   = blockIdx.x / ntiles;
    const int t0  = (blockIdx.x % ntiles) * FBM;

    float dv = dur[b * S_FIX + tid];
    s_scan[tid] = dv;
    __syncthreads();
    #pragma unroll
    for (int off = 1; off < S_FIX; off <<= 1) {
        float cur = s_scan[tid];
        float add = (tid >= off) ? s_scan[tid - off] : 0.0f;
        __syncthreads();
        s_scan[tid] = cur + add;
        __syncthreads();
    }
    {
        float e = s_scan[tid];
        float c = e - 0.5f * dv;
        float r = rng[b * S_FIX + tid];
        s_c[tid] = c; s_ir2[tid] = 1.0f / (r * r);
    }
    __syncthreads();
    {
        float cc = s_c[tid], ir = s_ir2[tid];
        #pragma unroll 4
        for (int tl = 0; tl < FBM; ++tl) {
            float tt = (float)(t0 + tl);
            float df = tt - cc;
            s_w[tl][tid] = __expf(-ir * df * df);
        }
    }
    __syncthreads();
    {
        const int t = tid & 31, ch = tid >> 5;
        float ps = 0.0f;
        #pragma unroll 8
        for (int j = 0; j < 32; ++j) ps += s_w[t][ch * 32 + ((j + t) & 31)];
        s_part[ch][t] = ps;
    }
    __syncthreads();
    if (tid < FBM) {
        float w2 = s_part[0][tid] + s_part[1][tid] + s_part[2][tid] + s_part[3][tid]
                 + s_part[4][tid] + s_part[5][tid] + s_part[6][tid] + s_part[7][tid] + 1e-20f;
        s_winv[tid] = 1.0f / w2;
    }
    __syncthreads();

    const int dq = tid & 63, tg = tid >> 6;
    float4 acc[8];
    #pragma unroll
    for (int i = 0; i < 8; ++i) acc[i] = make_float4(0.f, 0.f, 0.f, 0.f);
    const float* encb = enc + (size_t)b * S_FIX * D + (size_t)dq * 4;
    #pragma unroll 4
    for (int s = 0; s < S_FIX; ++s) {
        float4 ev = *(const float4*)(encb + (size_t)s * D);
        #pragma unroll
        for (int i = 0; i < 8; ++i) {
            float wv = s_w[tg * 8 + i][s];
            acc[i].x = fmaf(wv, ev.x, acc[i].x);
            acc[i].y = fmaf(wv, ev.y, acc[i].y);
            acc[i].z = fmaf(wv, ev.z, acc[i].z);
            acc[i].w = fmaf(wv, ev.w, acc[i].w);
        }
    }
    const float kf = -logf(10000.0f) / (float)D;
    const int d0 = dq * 4;
    const float f0 = __expf(kf * (float)(d0));
    const float f2 = __expf(kf * (float)(d0 + 2));
    float* outb = out + (size_t)b * T * D + (size_t)t0 * D + d0;
    #pragma unroll
    for (int i = 0; i < 8; ++i) {
        const int tl = tg * 8 + i;
        const float inv = s_winv[tl];
        const float tt = (float)(t0 + tl);
        const float a0 = tt * f0, a2 = tt * f2;
        float4 o;
        o.x = acc[i].x * inv + __sinf(a0);
        o.y = acc[i].y * inv + __cosf(a0);
        o.z = acc[i].z * inv + __sinf(a2);
        o.w = acc[i].w * inv + __cosf(a2);
        *(float4*)(outb + (size_t)tl * D) = o;
    }
}

extern "C" void kernel_launch(void* const* d_in, const int* in_sizes, int n_in,
                              void* d_out, int out_size, void* d_ws, size_t ws_size,
                              hipStream_t stream) {
    const float* enc = (const float*)d_in[0];
    const float* dur = (const float*)d_in[1];
    const float* rng = (const float*)d_in[2];
    float* out = (float*)d_out;

    const int S  = S_FIX;
    const int BS = in_sizes[1];
    const int B  = BS / S;
    const int D  = in_sizes[0] / BS;
    const int T  = out_size / (B * D);

    const size_t need = (size_t)B * D * S * sizeof(unsigned short);  // 4 MB

    if (D == D_FIX && S == S_FIX && (T % (BM * NTILE)) == 0 && ws_size >= need) {
        unsigned short* encT = (unsigned short*)d_ws;
        hipLaunchKernelGGL(transpose_enc_bf16, dim3(B * (S / 8) * D / 256), dim3(256),
                           0, stream, enc, encT);
        const int grid = B * (T / (BM * NTILE));   // 32*8 = 256
        hipLaunchKernelGGL(gauss_fused4, dim3(grid), dim3(512), 0, stream,
                           dur, rng, encT, out, T);
    } else {
        const int ntiles = T / FBM;
        hipLaunchKernelGGL(gauss_up_f32, dim3(B * ntiles), dim3(BLOCK), 0, stream,
                           enc, dur, rng, out, T, D, ntiles);
    }
}